// Round 2
// baseline (1973.130 us; speedup 1.0000x reference)
//
#include <hip/hip_runtime.h>
#include <hip/hip_bf16.h>

// ---------------- degree ----------------
__global__ void degree_kernel(const int* __restrict__ dst, float* __restrict__ deg, int E) {
    int i = blockIdx.x * blockDim.x + threadIdx.x;
    if (i < E) atomicAdd(&deg[dst[i]], 1.0f);
}

__global__ void rsqrt_kernel(float* __restrict__ dis, int N) {
    int i = blockIdx.x * blockDim.x + threadIdx.x;
    if (i < N) dis[i] = rsqrtf(dis[i] + 1.0f);
}

// ---------------- simple GEMM: out[N,F] = X[N,K] @ W[K,F], fp32 accum ----------------
template <int K, int F>
__global__ void gemm_kernel(const float* __restrict__ X, const float* __restrict__ W,
                            float* __restrict__ out, int N) {
    __shared__ float Wl[K * F];
    for (int i = threadIdx.x; i < K * F; i += blockDim.x)
        Wl[i] = W[i];
    __syncthreads();
    int i = blockIdx.x * blockDim.x + threadIdx.x;
    if (i >= N * F) return;
    int n = i / F, f = i - n * F;
    const float* xr = X + (size_t)n * K;
    float acc = 0.f;
#pragma unroll
    for (int k = 0; k < K; ++k) acc += xr[k] * Wl[k * F + f];
    out[i] = acc;
}

// ---------------- edge scatter: agg[dst] += h[src] * dis[src]*dis[dst] ----------------
template <int F>
__global__ void scatter_kernel(const int* __restrict__ src, const int* __restrict__ dst,
                               const float* __restrict__ dis, const float* __restrict__ h,
                               float* __restrict__ agg, int E) {
    constexpr int C = F / 4;  // float4 chunks per edge
    int i = blockIdx.x * blockDim.x + threadIdx.x;
    int total = E * C;
    if (i >= total) return;
    int e = i / C;
    int f = (i - e * C) * 4;
    int s = src[e], d = dst[e];
    float w = dis[s] * dis[d];
    const float4 v = *(const float4*)(h + (size_t)s * F + f);
    float* ap = agg + (size_t)d * F + f;
    atomicAdd(ap + 0, v.x * w);
    atomicAdd(ap + 1, v.y * w);
    atomicAdd(ap + 2, v.z * w);
    atomicAdd(ap + 3, v.w * w);
}

// ---------------- epilogues ----------------
template <int F>
__global__ void epilogue_relu(float* __restrict__ agg, const float* __restrict__ h,
                              const float* __restrict__ dis, const float* __restrict__ b,
                              int N) {
    int i = blockIdx.x * blockDim.x + threadIdx.x;
    if (i >= N * F) return;
    int n = i / F, f = i - n * F;
    float d2 = dis[n];
    d2 *= d2;
    float v = agg[i] + h[i] * d2 + b[f];
    agg[i] = fmaxf(v, 0.f);
}

template <int F>
__global__ void epilogue_sigmoid(const float* __restrict__ agg, const float* __restrict__ h,
                                 const float* __restrict__ dis, const float* __restrict__ b,
                                 float* __restrict__ out, int N) {
    int i = blockIdx.x * blockDim.x + threadIdx.x;
    if (i >= N * F) return;
    int n = i / F, f = i - n * F;
    float d2 = dis[n];
    d2 *= d2;
    float v = agg[i] + h[i] * d2 + b[f];
    out[i] = 1.f / (1.f + expf(-v));
}

extern "C" void kernel_launch(void* const* d_in, const int* in_sizes, int n_in,
                              void* d_out, int out_size, void* d_ws, size_t ws_size,
                              hipStream_t stream) {
    const float* x  = (const float*)d_in[0];
    const int*   ei = (const int*)d_in[1];
    const float* W1 = (const float*)d_in[2];
    const float* b1 = (const float*)d_in[3];
    const float* W2 = (const float*)d_in[4];
    const float* b2 = (const float*)d_in[5];

    constexpr int LAT = 64, HID = 96, OUTF = 64;
    const int E = in_sizes[1] / 2;
    const int N = in_sizes[0] / LAT;
    const int* src = ei;
    const int* dst = ei + E;

    // workspace layout (fp32)
    float* ws  = (float*)d_ws;
    size_t disPad = (size_t)((N + 4095) / 4096) * 4096;  // keep 16B alignment
    float* dis = ws;                         // N
    float* h   = ws + disPad;                // N*HID (also reused for h2: N*OUTF)
    float* agg = h + (size_t)N * HID;        // N*HID (also reused for agg2: N*OUTF)

    const int B = 256;
    auto blocks = [](long total, int b) { return (int)((total + b - 1) / b); };

    // 1) degree -> dis
    hipMemsetAsync(dis, 0, (size_t)N * sizeof(float), stream);
    degree_kernel<<<blocks(E, B), B, 0, stream>>>(dst, dis, E);
    rsqrt_kernel<<<blocks(N, B), B, 0, stream>>>(dis, N);

    // 2) h = x @ W1
    gemm_kernel<LAT, HID>
        <<<blocks((long)N * HID, B), B, 0, stream>>>(x, W1, h, N);

    // 3) scatter layer 1
    hipMemsetAsync(agg, 0, (size_t)N * HID * sizeof(float), stream);
    scatter_kernel<HID>
        <<<blocks((long)E * (HID / 4), B), B, 0, stream>>>(src, dst, dis, h, agg, E);

    // 4) h1 = relu(agg + h*dis^2 + b1)  (in place in agg)
    epilogue_relu<HID><<<blocks((long)N * HID, B), B, 0, stream>>>(agg, h, dis, b1, N);

    // 5) h2 = h1 @ W2  (reuse h buffer)
    gemm_kernel<HID, OUTF>
        <<<blocks((long)N * OUTF, B), B, 0, stream>>>(agg, W2, h, N);

    // 6) scatter layer 2 (re-zero agg region first)
    hipMemsetAsync(agg, 0, (size_t)N * OUTF * sizeof(float), stream);
    scatter_kernel<OUTF>
        <<<blocks((long)E * (OUTF / 4), B), B, 0, stream>>>(src, dst, dis, h, agg, E);

    // 7) out = sigmoid(agg + h2*dis^2 + b2)
    epilogue_sigmoid<OUTF>
        <<<blocks((long)N * OUTF, B), B, 0, stream>>>(agg, h, dis, b2,
                                                      (float*)d_out, N);
}

// Round 3
// 485.887 us; speedup vs baseline: 4.0609x; 4.0609x over previous
//
#include <hip/hip_runtime.h>
#include <hip/hip_bf16.h>

// ============================ common small kernels ============================

__global__ void degree_int_kernel(const int* __restrict__ dst, int* __restrict__ cnt, int E) {
    int i = blockIdx.x * blockDim.x + threadIdx.x;
    if (i < E) atomicAdd(&cnt[dst[i]], 1);
}

__global__ void dis_from_cnt_kernel(const int* __restrict__ cnt, float* __restrict__ dis, int N) {
    int i = blockIdx.x * blockDim.x + threadIdx.x;
    if (i < N) dis[i] = rsqrtf((float)cnt[i] + 1.0f);
}

// single-block exclusive scan: cursor[i] = sum(cnt[0..i-1])
__global__ __launch_bounds__(1024) void scan_kernel(const int* __restrict__ cnt,
                                                    int* __restrict__ cursor, int N) {
    constexpr int T = 1024;
    __shared__ int sums[T];
    int t = threadIdx.x;
    int ch = (N + T - 1) / T;
    int base = t * ch;
    int local = 0;
    for (int k = 0; k < ch; ++k) {
        int idx = base + k;
        if (idx < N) local += cnt[idx];
    }
    sums[t] = local;
    __syncthreads();
    for (int off = 1; off < T; off <<= 1) {
        int add = (t >= off) ? sums[t - off] : 0;
        __syncthreads();
        sums[t] += add;
        __syncthreads();
    }
    int run = sums[t] - local;  // exclusive prefix of this thread's chunk
    for (int k = 0; k < ch; ++k) {
        int idx = base + k;
        if (idx < N) {
            cursor[idx] = run;
            run += cnt[idx];
        }
    }
}

// fill CSR: cursor starts as exclusive offsets, ends as inclusive ends
__global__ void fill_kernel(const int* __restrict__ src, const int* __restrict__ dst,
                            int* __restrict__ cursor, int* __restrict__ csr_src, int E) {
    int e = blockIdx.x * blockDim.x + threadIdx.x;
    if (e >= E) return;
    int pos = atomicAdd(&cursor[dst[e]], 1);
    csr_src[pos] = src[e];
}

// ---------------- simple GEMM: out[N,F] = X[N,K] @ W[K,F], fp32 accum ----------------
template <int K, int F>
__global__ void gemm_kernel(const float* __restrict__ X, const float* __restrict__ W,
                            float* __restrict__ out, int N) {
    __shared__ float Wl[K * F];
    for (int i = threadIdx.x; i < K * F; i += blockDim.x)
        Wl[i] = W[i];
    __syncthreads();
    int i = blockIdx.x * blockDim.x + threadIdx.x;
    if (i >= N * F) return;
    int n = i / F, f = i - n * F;
    const float* xr = X + (size_t)n * K;
    float acc = 0.f;
#pragma unroll
    for (int k = 0; k < K; ++k) acc += xr[k] * Wl[k * F + f];
    out[i] = acc;
}

// ============== CSR gather-aggregate with fused epilogue ==============
// out[n] = act( sum_{e: dst=n} h[src_e]*dis[src_e]*dis[n] + h[n]*dis[n]^2 + b )
template <int F, bool RELU>
__global__ void agg_kernel(const int* __restrict__ cursor, const int* __restrict__ csr_src,
                           const float* __restrict__ dis, const float* __restrict__ h,
                           const float* __restrict__ b, float* __restrict__ out, int N) {
    constexpr int C = F / 4;
    int i = blockIdx.x * blockDim.x + threadIdx.x;
    if (i >= N * C) return;
    int n = i / C;
    int c = (i - n * C) * 4;
    int beg = (n == 0) ? 0 : cursor[n - 1];
    int end = cursor[n];
    float dn = dis[n];
    float ax = 0.f, ay = 0.f, az = 0.f, aw = 0.f;
    for (int j = beg; j < end; ++j) {
        int s = csr_src[j];
        float w = dis[s] * dn;
        const float4 v = *(const float4*)(h + (size_t)s * F + c);
        ax += v.x * w;
        ay += v.y * w;
        az += v.z * w;
        aw += v.w * w;
    }
    float d2 = dn * dn;
    const float4 hv = *(const float4*)(h + (size_t)n * F + c);
    const float4 bv = *(const float4*)(b + c);
    float4 r;
    r.x = ax + hv.x * d2 + bv.x;
    r.y = ay + hv.y * d2 + bv.y;
    r.z = az + hv.z * d2 + bv.z;
    r.w = aw + hv.w * d2 + bv.w;
    if (RELU) {
        r.x = fmaxf(r.x, 0.f);
        r.y = fmaxf(r.y, 0.f);
        r.z = fmaxf(r.z, 0.f);
        r.w = fmaxf(r.w, 0.f);
    } else {
        r.x = 1.f / (1.f + expf(-r.x));
        r.y = 1.f / (1.f + expf(-r.y));
        r.z = 1.f / (1.f + expf(-r.z));
        r.w = 1.f / (1.f + expf(-r.w));
    }
    *(float4*)(out + (size_t)n * F + c) = r;
}

// ============================ fallback (round-2 proven) ============================

__global__ void degree_f_kernel(const int* __restrict__ dst, float* __restrict__ deg, int E) {
    int i = blockIdx.x * blockDim.x + threadIdx.x;
    if (i < E) atomicAdd(&deg[dst[i]], 1.0f);
}

__global__ void rsqrt_kernel(float* __restrict__ dis, int N) {
    int i = blockIdx.x * blockDim.x + threadIdx.x;
    if (i < N) dis[i] = rsqrtf(dis[i] + 1.0f);
}

template <int F>
__global__ void scatter_kernel(const int* __restrict__ src, const int* __restrict__ dst,
                               const float* __restrict__ dis, const float* __restrict__ h,
                               float* __restrict__ agg, int E) {
    constexpr int C = F / 4;
    int i = blockIdx.x * blockDim.x + threadIdx.x;
    if (i >= E * C) return;
    int e = i / C;
    int f = (i - e * C) * 4;
    int s = src[e], d = dst[e];
    float w = dis[s] * dis[d];
    const float4 v = *(const float4*)(h + (size_t)s * F + f);
    float* ap = agg + (size_t)d * F + f;
    atomicAdd(ap + 0, v.x * w);
    atomicAdd(ap + 1, v.y * w);
    atomicAdd(ap + 2, v.z * w);
    atomicAdd(ap + 3, v.w * w);
}

template <int F>
__global__ void epilogue_relu(float* __restrict__ agg, const float* __restrict__ h,
                              const float* __restrict__ dis, const float* __restrict__ b, int N) {
    int i = blockIdx.x * blockDim.x + threadIdx.x;
    if (i >= N * F) return;
    int n = i / F, f = i - n * F;
    float d2 = dis[n];
    d2 *= d2;
    float v = agg[i] + h[i] * d2 + b[f];
    agg[i] = fmaxf(v, 0.f);
}

template <int F>
__global__ void epilogue_sigmoid(const float* __restrict__ agg, const float* __restrict__ h,
                                 const float* __restrict__ dis, const float* __restrict__ b,
                                 float* __restrict__ out, int N) {
    int i = blockIdx.x * blockDim.x + threadIdx.x;
    if (i >= N * F) return;
    int n = i / F, f = i - n * F;
    float d2 = dis[n];
    d2 *= d2;
    float v = agg[i] + h[i] * d2 + b[f];
    out[i] = 1.f / (1.f + expf(-v));
}

// ============================ launch ============================

extern "C" void kernel_launch(void* const* d_in, const int* in_sizes, int n_in,
                              void* d_out, int out_size, void* d_ws, size_t ws_size,
                              hipStream_t stream) {
    const float* x  = (const float*)d_in[0];
    const int*   ei = (const int*)d_in[1];
    const float* W1 = (const float*)d_in[2];
    const float* b1 = (const float*)d_in[3];
    const float* W2 = (const float*)d_in[4];
    const float* b2 = (const float*)d_in[5];

    constexpr int LAT = 64, HID = 96, OUTF = 64;
    const int E = in_sizes[1] / 2;
    const int N = in_sizes[0] / LAT;
    const int* src = ei;
    const int* dst = ei + E;

    const int B = 256;
    auto blocks = [](long total, int b) { return (int)((total + b - 1) / b); };

    size_t Npad = (size_t)((N + 1023) / 1024) * 1024;
    size_t Epad = (size_t)((E + 3) / 4) * 4;
    size_t needed = (3 * Npad + Epad + 2 * (size_t)N * HID) * sizeof(float);

    if (ws_size >= needed) {
        // ---------------- CSR gather path ----------------
        int*   cnt     = (int*)d_ws;                    // N
        int*   cursor  = cnt + Npad;                    // N
        float* dis     = (float*)(cursor + Npad);       // N
        int*   csr_src = (int*)(dis + Npad);            // E
        float* A       = (float*)(csr_src + Epad);      // N*HID  (h, later h2)
        float* Bb      = A + (size_t)N * HID;           // N*HID  (h1)

        // degree + dis + CSR offsets
        hipMemsetAsync(cnt, 0, (size_t)N * sizeof(int), stream);
        degree_int_kernel<<<blocks(E, B), B, 0, stream>>>(dst, cnt, E);
        dis_from_cnt_kernel<<<blocks(N, B), B, 0, stream>>>(cnt, dis, N);
        scan_kernel<<<1, 1024, 0, stream>>>(cnt, cursor, N);
        fill_kernel<<<blocks(E, B), B, 0, stream>>>(src, dst, cursor, csr_src, E);

        // layer 1: h = x@W1 ; h1 = relu(agg(h) + h*dis^2 + b1)
        gemm_kernel<LAT, HID><<<blocks((long)N * HID, B), B, 0, stream>>>(x, W1, A, N);
        agg_kernel<HID, true>
            <<<blocks((long)N * (HID / 4), B), B, 0, stream>>>(cursor, csr_src, dis, A, b1, Bb, N);

        // layer 2: h2 = h1@W2 ; out = sigmoid(agg(h2) + h2*dis^2 + b2)
        gemm_kernel<HID, OUTF><<<blocks((long)N * OUTF, B), B, 0, stream>>>(Bb, W2, A, N);
        agg_kernel<OUTF, false>
            <<<blocks((long)N * (OUTF / 4), B), B, 0, stream>>>(cursor, csr_src, dis, A, b2,
                                                                (float*)d_out, N);
    } else {
        // ---------------- fallback: atomic scatter path (round-2) ----------------
        float* ws  = (float*)d_ws;
        size_t disPad = (size_t)((N + 4095) / 4096) * 4096;
        float* dis = ws;
        float* h   = ws + disPad;
        float* agg = h + (size_t)N * HID;

        hipMemsetAsync(dis, 0, (size_t)N * sizeof(float), stream);
        degree_f_kernel<<<blocks(E, B), B, 0, stream>>>(dst, dis, E);
        rsqrt_kernel<<<blocks(N, B), B, 0, stream>>>(dis, N);

        gemm_kernel<LAT, HID><<<blocks((long)N * HID, B), B, 0, stream>>>(x, W1, h, N);
        hipMemsetAsync(agg, 0, (size_t)N * HID * sizeof(float), stream);
        scatter_kernel<HID>
            <<<blocks((long)E * (HID / 4), B), B, 0, stream>>>(src, dst, dis, h, agg, E);
        epilogue_relu<HID><<<blocks((long)N * HID, B), B, 0, stream>>>(agg, h, dis, b1, N);

        gemm_kernel<HID, OUTF><<<blocks((long)N * OUTF, B), B, 0, stream>>>(agg, W2, h, N);
        hipMemsetAsync(agg, 0, (size_t)N * OUTF * sizeof(float), stream);
        scatter_kernel<OUTF>
            <<<blocks((long)E * (OUTF / 4), B), B, 0, stream>>>(src, dst, dis, h, agg, E);
        epilogue_sigmoid<OUTF>
            <<<blocks((long)N * OUTF, B), B, 0, stream>>>(agg, h, dis, b2, (float*)d_out, N);
    }
}

// Round 4
// 289.805 us; speedup vs baseline: 6.8085x; 1.6766x over previous
//
#include <hip/hip_runtime.h>
#include <hip/hip_bf16.h>

// ============================ degree / dis ============================

__global__ void degree_int_kernel(const int* __restrict__ dst, int* __restrict__ cnt, int E) {
    int i = blockIdx.x * blockDim.x + threadIdx.x;
    if (i < E) atomicAdd(&cnt[dst[i]], 1);
}

__global__ void dis_from_cnt_kernel(const int* __restrict__ cnt, float* __restrict__ dis, int N) {
    int i = blockIdx.x * blockDim.x + threadIdx.x;
    if (i < N) dis[i] = rsqrtf((float)cnt[i] + 1.0f);
}

// ============================ multi-block scan ============================
// pass A: per-block (1024 elems) totals
__global__ __launch_bounds__(256) void scan_block_sum(const int* __restrict__ cnt,
                                                      int* __restrict__ partial, int N) {
    __shared__ int s[256];
    int t = threadIdx.x;
    int base = blockIdx.x * 1024 + t * 4;
    int v = 0;
#pragma unroll
    for (int k = 0; k < 4; ++k) {
        int idx = base + k;
        if (idx < N) v += cnt[idx];
    }
    s[t] = v;
    __syncthreads();
    for (int off = 128; off > 0; off >>= 1) {
        if (t < off) s[t] += s[t + off];
        __syncthreads();
    }
    if (t == 0) partial[blockIdx.x] = s[0];
}

// pass B: one wave scans <=64 partials to exclusive offsets
__global__ __launch_bounds__(64) void scan_partials(int* __restrict__ partial, int G) {
    int t = threadIdx.x;
    int o = (t < G) ? partial[t] : 0;
    int v = o;
#pragma unroll
    for (int off = 1; off < 64; off <<= 1) {
        int u = __shfl_up(v, off, 64);
        if (t >= off) v += u;
    }
    if (t < G) partial[t] = v - o;  // exclusive
}

// pass C: per-block rescan, write exclusive offsets
__global__ __launch_bounds__(256) void scan_write(const int* __restrict__ cnt,
                                                  const int* __restrict__ partial,
                                                  int* __restrict__ cursor, int N) {
    __shared__ int s[256];
    int t = threadIdx.x;
    int base = blockIdx.x * 1024 + t * 4;
    int loc[4];
    int v = 0;
#pragma unroll
    for (int k = 0; k < 4; ++k) {
        int idx = base + k;
        loc[k] = (idx < N) ? cnt[idx] : 0;
        v += loc[k];
    }
    s[t] = v;
    __syncthreads();
    for (int off = 1; off < 256; off <<= 1) {
        int add = (t >= off) ? s[t - off] : 0;
        __syncthreads();
        s[t] += add;
        __syncthreads();
    }
    int run = partial[blockIdx.x] + s[t] - v;  // exclusive prefix at this thread's base
#pragma unroll
    for (int k = 0; k < 4; ++k) {
        int idx = base + k;
        if (idx < N) {
            cursor[idx] = run;
            run += loc[k];
        }
    }
}

// legacy single-block scan (fallback if G > 64)
__global__ __launch_bounds__(1024) void scan_kernel(const int* __restrict__ cnt,
                                                    int* __restrict__ cursor, int N) {
    constexpr int T = 1024;
    __shared__ int sums[T];
    int t = threadIdx.x;
    int ch = (N + T - 1) / T;
    int base = t * ch;
    int local = 0;
    for (int k = 0; k < ch; ++k) {
        int idx = base + k;
        if (idx < N) local += cnt[idx];
    }
    sums[t] = local;
    __syncthreads();
    for (int off = 1; off < T; off <<= 1) {
        int add = (t >= off) ? sums[t - off] : 0;
        __syncthreads();
        sums[t] += add;
        __syncthreads();
    }
    int run = sums[t] - local;
    for (int k = 0; k < ch; ++k) {
        int idx = base + k;
        if (idx < N) {
            cursor[idx] = run;
            run += cnt[idx];
        }
    }
}

// fill CSR: cursor starts as exclusive offsets, ends as inclusive ends
__global__ void fill_kernel(const int* __restrict__ src, const int* __restrict__ dst,
                            int* __restrict__ cursor, int* __restrict__ csr_src, int E) {
    int e = blockIdx.x * blockDim.x + threadIdx.x;
    if (e >= E) return;
    int pos = atomicAdd(&cursor[dst[e]], 1);
    csr_src[pos] = src[e];
}

// ============== tiled GEMM: out[N,F] = X[N,K] @ W[K,F], fp32 ==============
// 256 threads; TM=64 nodes/block; thread (tn,tf) computes RN=4 nodes x RF feats.
template <int K, int F, int RF>
__global__ __launch_bounds__(256) void gemm_tiled(const float* __restrict__ X,
                                                  const float* __restrict__ W,
                                                  float* __restrict__ out, int N) {
    constexpr int TM = 64, RN = 4;
    static_assert(F == 16 * RF, "");
    __shared__ float Xs[TM * (K + 1)];
    __shared__ float Ws[K * F];

    const int n0 = blockIdx.x * TM;
    const int t = threadIdx.x;

    // stage W (coalesced float4)
    for (int i = t; i < (K * F) / 4; i += 256)
        ((float4*)Ws)[i] = ((const float4*)W)[i];
    // stage X tile (float4 global, scalar LDS stores into padded rows)
    for (int i = t; i < (TM * K) / 4; i += 256) {
        int row = i / (K / 4);
        int c4 = (i - row * (K / 4)) * 4;
        float4 v = make_float4(0.f, 0.f, 0.f, 0.f);
        if (n0 + row < N) v = *(const float4*)(X + (size_t)(n0 + row) * K + c4);
        float* p = Xs + row * (K + 1) + c4;
        p[0] = v.x; p[1] = v.y; p[2] = v.z; p[3] = v.w;
    }
    __syncthreads();

    const int tn = t >> 4;   // 0..15 -> node group
    const int tf = t & 15;   // 0..15 -> feature group
    float acc[RN][RF] = {};
#pragma unroll 4
    for (int k = 0; k < K; ++k) {
        float xv[RN];
#pragma unroll
        for (int i = 0; i < RN; ++i) xv[i] = Xs[(tn * RN + i) * (K + 1) + k];
        float wv[RF];
#pragma unroll
        for (int j = 0; j < RF / 2; ++j) {
            float2 w2 = *(const float2*)(Ws + k * F + tf * RF + 2 * j);
            wv[2 * j] = w2.x;
            wv[2 * j + 1] = w2.y;
        }
#pragma unroll
        for (int i = 0; i < RN; ++i)
#pragma unroll
            for (int j = 0; j < RF; ++j) acc[i][j] += xv[i] * wv[j];
    }

#pragma unroll
    for (int i = 0; i < RN; ++i) {
        int n = n0 + tn * RN + i;
        if (n < N) {
            float* op = out + (size_t)n * F + tf * RF;
#pragma unroll
            for (int j = 0; j < RF; ++j) op[j] = acc[i][j];
        }
    }
}

// ============== CSR gather-aggregate with fused epilogue ==============
template <int F, bool RELU>
__global__ void agg_kernel(const int* __restrict__ cursor, const int* __restrict__ csr_src,
                           const float* __restrict__ dis, const float* __restrict__ h,
                           const float* __restrict__ b, float* __restrict__ out, int N) {
    constexpr int C = F / 4;
    int i = blockIdx.x * blockDim.x + threadIdx.x;
    if (i >= N * C) return;
    int n = i / C;
    int c = (i - n * C) * 4;
    int beg = (n == 0) ? 0 : cursor[n - 1];
    int end = cursor[n];
    float dn = dis[n];
    float ax = 0.f, ay = 0.f, az = 0.f, aw = 0.f;
    for (int j = beg; j < end; ++j) {
        int s = csr_src[j];
        float w = dis[s] * dn;
        const float4 v = *(const float4*)(h + (size_t)s * F + c);
        ax += v.x * w;
        ay += v.y * w;
        az += v.z * w;
        aw += v.w * w;
    }
    float d2 = dn * dn;
    const float4 hv = *(const float4*)(h + (size_t)n * F + c);
    const float4 bv = *(const float4*)(b + c);
    float4 r;
    r.x = ax + hv.x * d2 + bv.x;
    r.y = ay + hv.y * d2 + bv.y;
    r.z = az + hv.z * d2 + bv.z;
    r.w = aw + hv.w * d2 + bv.w;
    if (RELU) {
        r.x = fmaxf(r.x, 0.f);
        r.y = fmaxf(r.y, 0.f);
        r.z = fmaxf(r.z, 0.f);
        r.w = fmaxf(r.w, 0.f);
    } else {
        r.x = 1.f / (1.f + expf(-r.x));
        r.y = 1.f / (1.f + expf(-r.y));
        r.z = 1.f / (1.f + expf(-r.z));
        r.w = 1.f / (1.f + expf(-r.w));
    }
    *(float4*)(out + (size_t)n * F + c) = r;
}

// ============================ fallback (round-2 proven) ============================

__global__ void degree_f_kernel(const int* __restrict__ dst, float* __restrict__ deg, int E) {
    int i = blockIdx.x * blockDim.x + threadIdx.x;
    if (i < E) atomicAdd(&deg[dst[i]], 1.0f);
}

__global__ void rsqrt_kernel(float* __restrict__ dis, int N) {
    int i = blockIdx.x * blockDim.x + threadIdx.x;
    if (i < N) dis[i] = rsqrtf(dis[i] + 1.0f);
}

template <int F>
__global__ void scatter_kernel(const int* __restrict__ src, const int* __restrict__ dst,
                               const float* __restrict__ dis, const float* __restrict__ h,
                               float* __restrict__ agg, int E) {
    constexpr int C = F / 4;
    int i = blockIdx.x * blockDim.x + threadIdx.x;
    if (i >= E * C) return;
    int e = i / C;
    int f = (i - e * C) * 4;
    int s = src[e], d = dst[e];
    float w = dis[s] * dis[d];
    const float4 v = *(const float4*)(h + (size_t)s * F + f);
    float* ap = agg + (size_t)d * F + f;
    atomicAdd(ap + 0, v.x * w);
    atomicAdd(ap + 1, v.y * w);
    atomicAdd(ap + 2, v.z * w);
    atomicAdd(ap + 3, v.w * w);
}

template <int F>
__global__ void epilogue_relu(float* __restrict__ agg, const float* __restrict__ h,
                              const float* __restrict__ dis, const float* __restrict__ b, int N) {
    int i = blockIdx.x * blockDim.x + threadIdx.x;
    if (i >= N * F) return;
    int n = i / F, f = i - n * F;
    float d2 = dis[n];
    d2 *= d2;
    float v = agg[i] + h[i] * d2 + b[f];
    agg[i] = fmaxf(v, 0.f);
}

template <int F>
__global__ void epilogue_sigmoid(const float* __restrict__ agg, const float* __restrict__ h,
                                 const float* __restrict__ dis, const float* __restrict__ b,
                                 float* __restrict__ out, int N) {
    int i = blockIdx.x * blockDim.x + threadIdx.x;
    if (i >= N * F) return;
    int n = i / F, f = i - n * F;
    float d2 = dis[n];
    d2 *= d2;
    float v = agg[i] + h[i] * d2 + b[f];
    out[i] = 1.f / (1.f + expf(-v));
}

// ============================ launch ============================

extern "C" void kernel_launch(void* const* d_in, const int* in_sizes, int n_in,
                              void* d_out, int out_size, void* d_ws, size_t ws_size,
                              hipStream_t stream) {
    const float* x  = (const float*)d_in[0];
    const int*   ei = (const int*)d_in[1];
    const float* W1 = (const float*)d_in[2];
    const float* b1 = (const float*)d_in[3];
    const float* W2 = (const float*)d_in[4];
    const float* b2 = (const float*)d_in[5];

    constexpr int LAT = 64, HID = 96, OUTF = 64;
    const int E = in_sizes[1] / 2;
    const int N = in_sizes[0] / LAT;
    const int* src = ei;
    const int* dst = ei + E;

    const int B = 256;
    auto blocks = [](long total, int b) { return (int)((total + b - 1) / b); };

    size_t Npad = (size_t)((N + 1023) / 1024) * 1024;
    size_t Epad = (size_t)((E + 3) / 4) * 4;
    size_t needed = (3 * Npad + Epad + 1024 + 2 * (size_t)N * HID) * sizeof(float);

    if (ws_size >= needed) {
        // ---------------- CSR gather path ----------------
        int*   cnt     = (int*)d_ws;                    // Npad
        int*   cursor  = cnt + Npad;                    // Npad
        float* dis     = (float*)(cursor + Npad);       // Npad
        int*   csr_src = (int*)(dis + Npad);            // Epad
        int*   partial = csr_src + Epad;                // 1024
        float* A       = (float*)(partial + 1024);      // N*HID  (h, later h2)
        float* Bb      = A + (size_t)N * HID;           // N*HID  (h1)

        // degree + dis + CSR offsets
        hipMemsetAsync(cnt, 0, (size_t)N * sizeof(int), stream);
        degree_int_kernel<<<blocks(E, B), B, 0, stream>>>(dst, cnt, E);
        dis_from_cnt_kernel<<<blocks(N, B), B, 0, stream>>>(cnt, dis, N);
        int G = blocks(N, 1024);
        if (G <= 64) {
            scan_block_sum<<<G, 256, 0, stream>>>(cnt, partial, N);
            scan_partials<<<1, 64, 0, stream>>>(partial, G);
            scan_write<<<G, 256, 0, stream>>>(cnt, partial, cursor, N);
        } else {
            scan_kernel<<<1, 1024, 0, stream>>>(cnt, cursor, N);
        }
        fill_kernel<<<blocks(E, B), B, 0, stream>>>(src, dst, cursor, csr_src, E);

        // layer 1: h = x@W1 ; h1 = relu(agg(h) + h*dis^2 + b1)
        gemm_tiled<LAT, HID, 6><<<blocks(N, 64), 256, 0, stream>>>(x, W1, A, N);
        agg_kernel<HID, true>
            <<<blocks((long)N * (HID / 4), B), B, 0, stream>>>(cursor, csr_src, dis, A, b1, Bb, N);

        // layer 2: h2 = h1@W2 ; out = sigmoid(agg(h2) + h2*dis^2 + b2)
        gemm_tiled<HID, OUTF, 4><<<blocks(N, 64), 256, 0, stream>>>(Bb, W2, A, N);
        agg_kernel<OUTF, false>
            <<<blocks((long)N * (OUTF / 4), B), B, 0, stream>>>(cursor, csr_src, dis, A, b2,
                                                                (float*)d_out, N);
    } else {
        // ---------------- fallback: atomic scatter path (round-2) ----------------
        float* ws  = (float*)d_ws;
        size_t disPad = (size_t)((N + 4095) / 4096) * 4096;
        float* dis = ws;
        float* h   = ws + disPad;
        float* agg = h + (size_t)N * HID;

        hipMemsetAsync(dis, 0, (size_t)N * sizeof(float), stream);
        degree_f_kernel<<<blocks(E, B), B, 0, stream>>>(dst, dis, E);
        rsqrt_kernel<<<blocks(N, B), B, 0, stream>>>(dis, N);

        gemm_tiled<LAT, HID, 6><<<blocks(N, 64), 256, 0, stream>>>(x, W1, h, N);
        hipMemsetAsync(agg, 0, (size_t)N * HID * sizeof(float), stream);
        scatter_kernel<HID>
            <<<blocks((long)E * (HID / 4), B), B, 0, stream>>>(src, dst, dis, h, agg, E);
        epilogue_relu<HID><<<blocks((long)N * HID, B), B, 0, stream>>>(agg, h, dis, b1, N);

        gemm_tiled<HID, OUTF, 4><<<blocks(N, 64), 256, 0, stream>>>(agg, W2, h, N);
        hipMemsetAsync(agg, 0, (size_t)N * OUTF * sizeof(float), stream);
        scatter_kernel<OUTF>
            <<<blocks((long)E * (OUTF / 4), B), B, 0, stream>>>(src, dst, dis, h, agg, E);
        epilogue_sigmoid<OUTF>
            <<<blocks((long)N * OUTF, B), B, 0, stream>>>(agg, h, dis, b2, (float*)d_out, N);
    }
}

// Round 5
// 277.087 us; speedup vs baseline: 7.1210x; 1.0459x over previous
//
#include <hip/hip_runtime.h>
#include <hip/hip_bf16.h>

// ==================== counting-sort CSR build (no device atomics) ====================
constexpr int G1 = 96;         // edge-chunk blocks
constexpr int RNODES = 25088;  // nodes per LDS range (u16 hist = 50176 B < 64 KB)

// K1: per-(block, node) histogram via LDS packed-u16 atomics
__global__ __launch_bounds__(256) void histo_kernel(const int* __restrict__ dst,
                                                    unsigned short* __restrict__ hist,
                                                    int E, int chunk, int ranges, int npad2) {
    __shared__ unsigned int h32[RNODES / 2];
    int g = blockIdx.x;
    int e0 = g * chunk;
    int e1 = min(e0 + chunk, E);
    for (int r = 0; r < ranges; ++r) {
        int base = r * RNODES;
        for (int i = threadIdx.x; i < RNODES / 2; i += 256) h32[i] = 0;
        __syncthreads();
        for (int e = e0 + threadIdx.x; e < e1; e += 256) {
            int d = dst[e] - base;
            if (d >= 0 && d < RNODES) atomicAdd(&h32[d >> 1], 1u << ((d & 1) * 16));
        }
        __syncthreads();
        for (int i = threadIdx.x; i < RNODES; i += 256) {
            unsigned int v = (h32[i >> 1] >> ((i & 1) * 16)) & 0xFFFFu;
            hist[(size_t)g * npad2 + base + i] = (unsigned short)v;
        }
        __syncthreads();
    }
}

// K2: cnt[d] = sum_g hist[g][d]; also dis[d] = rsqrt(cnt+1)
__global__ void colsum_kernel(const unsigned short* __restrict__ hist, int* __restrict__ cnt,
                              float* __restrict__ dis, int N, int npad2) {
    int d = blockIdx.x * blockDim.x + threadIdx.x;
    if (d >= N) return;
    int s = 0;
    for (int g = 0; g < G1; ++g) s += hist[(size_t)g * npad2 + d];
    cnt[d] = s;
    dis[d] = rsqrtf((float)s + 1.0f);
}

// K3: colbase[g][d] = cursor[d] + sum_{g'<g} hist[g'][d]
__global__ void colbase_kernel(const unsigned short* __restrict__ hist,
                               const int* __restrict__ cursor, int* __restrict__ colbase,
                               int N, int npad2) {
    int d = blockIdx.x * blockDim.x + threadIdx.x;
    if (d >= N) return;
    int run = cursor[d];
    for (int g = 0; g < G1; ++g) {
        colbase[(size_t)g * npad2 + d] = run;
        run += hist[(size_t)g * npad2 + d];
    }
}

// K4: fill csr_src with LDS-only atomics (local index within (block,range))
__global__ __launch_bounds__(256) void fill_fast_kernel(const int* __restrict__ src,
                                                        const int* __restrict__ dst,
                                                        const int* __restrict__ colbase,
                                                        int* __restrict__ csr_src,
                                                        int E, int chunk, int ranges, int npad2) {
    __shared__ unsigned int c32[RNODES / 2];
    int g = blockIdx.x;
    int e0 = g * chunk;
    int e1 = min(e0 + chunk, E);
    for (int r = 0; r < ranges; ++r) {
        int base = r * RNODES;
        for (int i = threadIdx.x; i < RNODES / 2; i += 256) c32[i] = 0;
        __syncthreads();
        for (int e = e0 + threadIdx.x; e < e1; e += 256) {
            int d = dst[e] - base;
            if (d >= 0 && d < RNODES) {
                unsigned int sh = (d & 1) * 16;
                unsigned int old = atomicAdd(&c32[d >> 1], 1u << sh);
                int local = (old >> sh) & 0xFFFF;
                int pos = colbase[(size_t)g * npad2 + base + d] + local;
                csr_src[pos] = src[e];
            }
        }
        __syncthreads();
    }
}

// ==================== multi-block scan (exclusive) ====================
__global__ __launch_bounds__(256) void scan_block_sum(const int* __restrict__ cnt,
                                                      int* __restrict__ partial, int N) {
    __shared__ int s[256];
    int t = threadIdx.x;
    int base = blockIdx.x * 1024 + t * 4;
    int v = 0;
#pragma unroll
    for (int k = 0; k < 4; ++k) {
        int idx = base + k;
        if (idx < N) v += cnt[idx];
    }
    s[t] = v;
    __syncthreads();
    for (int off = 128; off > 0; off >>= 1) {
        if (t < off) s[t] += s[t + off];
        __syncthreads();
    }
    if (t == 0) partial[blockIdx.x] = s[0];
}

__global__ __launch_bounds__(64) void scan_partials(int* __restrict__ partial, int G) {
    int t = threadIdx.x;
    int o = (t < G) ? partial[t] : 0;
    int v = o;
#pragma unroll
    for (int off = 1; off < 64; off <<= 1) {
        int u = __shfl_up(v, off, 64);
        if (t >= off) v += u;
    }
    if (t < G) partial[t] = v - o;
}

__global__ __launch_bounds__(256) void scan_write(const int* __restrict__ cnt,
                                                  const int* __restrict__ partial,
                                                  int* __restrict__ cursor, int N) {
    __shared__ int s[256];
    int t = threadIdx.x;
    int base = blockIdx.x * 1024 + t * 4;
    int loc[4];
    int v = 0;
#pragma unroll
    for (int k = 0; k < 4; ++k) {
        int idx = base + k;
        loc[k] = (idx < N) ? cnt[idx] : 0;
        v += loc[k];
    }
    s[t] = v;
    __syncthreads();
    for (int off = 1; off < 256; off <<= 1) {
        int add = (t >= off) ? s[t - off] : 0;
        __syncthreads();
        s[t] += add;
        __syncthreads();
    }
    int run = partial[blockIdx.x] + s[t] - v;
#pragma unroll
    for (int k = 0; k < 4; ++k) {
        int idx = base + k;
        if (idx < N) {
            cursor[idx] = run;
            run += loc[k];
        }
    }
}

__global__ __launch_bounds__(1024) void scan_kernel(const int* __restrict__ cnt,
                                                    int* __restrict__ cursor, int N) {
    constexpr int T = 1024;
    __shared__ int sums[T];
    int t = threadIdx.x;
    int ch = (N + T - 1) / T;
    int base = t * ch;
    int local = 0;
    for (int k = 0; k < ch; ++k) {
        int idx = base + k;
        if (idx < N) local += cnt[idx];
    }
    sums[t] = local;
    __syncthreads();
    for (int off = 1; off < T; off <<= 1) {
        int add = (t >= off) ? sums[t - off] : 0;
        __syncthreads();
        sums[t] += add;
        __syncthreads();
    }
    int run = sums[t] - local;
    for (int k = 0; k < ch; ++k) {
        int idx = base + k;
        if (idx < N) {
            cursor[idx] = run;
            run += cnt[idx];
        }
    }
}

// ==================== fallback CSR build (device atomics) ====================
__global__ void degree_int_kernel(const int* __restrict__ dst, int* __restrict__ cnt, int E) {
    int i = blockIdx.x * blockDim.x + threadIdx.x;
    if (i < E) atomicAdd(&cnt[dst[i]], 1);
}

__global__ void dis_from_cnt_kernel(const int* __restrict__ cnt, float* __restrict__ dis, int N) {
    int i = blockIdx.x * blockDim.x + threadIdx.x;
    if (i < N) dis[i] = rsqrtf((float)cnt[i] + 1.0f);
}

__global__ void zero_int_kernel(int* __restrict__ p, int N) {
    int i = blockIdx.x * blockDim.x + threadIdx.x;
    if (i < N) p[i] = 0;
}

__global__ void fill_atomic_kernel(const int* __restrict__ src, const int* __restrict__ dst,
                                   int* __restrict__ cursor_mut, int* __restrict__ csr_src,
                                   int E) {
    int e = blockIdx.x * blockDim.x + threadIdx.x;
    if (e >= E) return;
    int pos = atomicAdd(&cursor_mut[dst[e]], 1);
    csr_src[pos] = src[e];
}

// ==================== tiled GEMM with optional fused bias+relu ====================
// 256 threads; TM=64 nodes/block; thread (tn,tf) computes RN=4 nodes x RF feats.
template <int K, int F, int RF, bool BIAS_RELU>
__global__ __launch_bounds__(256) void gemm_tiled(const float* __restrict__ X,
                                                  const float* __restrict__ W,
                                                  const float* __restrict__ bias,
                                                  float* __restrict__ out, int N) {
    constexpr int TM = 64, RN = 4;
    static_assert(F == 16 * RF, "");
    __shared__ float Xs[TM * (K + 1)];
    __shared__ float Ws[K * F];

    const int n0 = blockIdx.x * TM;
    const int t = threadIdx.x;

    for (int i = t; i < (K * F) / 4; i += 256)
        ((float4*)Ws)[i] = ((const float4*)W)[i];
    for (int i = t; i < (TM * K) / 4; i += 256) {
        int row = i / (K / 4);
        int c4 = (i - row * (K / 4)) * 4;
        float4 v = make_float4(0.f, 0.f, 0.f, 0.f);
        if (n0 + row < N) v = *(const float4*)(X + (size_t)(n0 + row) * K + c4);
        float* p = Xs + row * (K + 1) + c4;
        p[0] = v.x; p[1] = v.y; p[2] = v.z; p[3] = v.w;
    }
    __syncthreads();

    const int tn = t >> 4;
    const int tf = t & 15;
    float acc[RN][RF] = {};
#pragma unroll 4
    for (int k = 0; k < K; ++k) {
        float xv[RN];
#pragma unroll
        for (int i = 0; i < RN; ++i) xv[i] = Xs[(tn * RN + i) * (K + 1) + k];
        float wv[RF];
#pragma unroll
        for (int j = 0; j < RF / 2; ++j) {
            float2 w2 = *(const float2*)(Ws + k * F + tf * RF + 2 * j);
            wv[2 * j] = w2.x;
            wv[2 * j + 1] = w2.y;
        }
#pragma unroll
        for (int i = 0; i < RN; ++i)
#pragma unroll
            for (int j = 0; j < RF; ++j) acc[i][j] += xv[i] * wv[j];
    }

    float breg[RF];
    if (BIAS_RELU) {
#pragma unroll
        for (int j = 0; j < RF; ++j) breg[j] = bias[tf * RF + j];
    }
#pragma unroll
    for (int i = 0; i < RN; ++i) {
        int n = n0 + tn * RN + i;
        if (n < N) {
            float* op = out + (size_t)n * F + tf * RF;
#pragma unroll
            for (int j = 0; j < RF; ++j) {
                float v = acc[i][j];
                if (BIAS_RELU) v = fmaxf(v + breg[j], 0.f);
                op[j] = v;
            }
        }
    }
}

// ==================== CSR gather-aggregate over 64 features ====================
// MODE 0: out = agg + X[n]*dn^2                 (pre-GEMM aggregation)
// MODE 1: out = sigmoid(agg + X[n]*dn^2 + b)    (final layer)
template <int MODE>
__global__ __launch_bounds__(256) void agg64_kernel(const int* __restrict__ cursor,
                                                    const int* __restrict__ cnt,
                                                    const int* __restrict__ csr_src,
                                                    const float* __restrict__ dis,
                                                    const float* __restrict__ X,
                                                    const float* __restrict__ b,
                                                    float* __restrict__ out, int N) {
    int i = blockIdx.x * 256 + threadIdx.x;
    int n = i >> 4;
    int c = (i & 15) * 4;
    if (n >= N) return;
    int beg = cursor[n];
    int end = beg + cnt[n];
    float dn = dis[n];
    float ax = 0.f, ay = 0.f, az = 0.f, aw = 0.f;
    for (int j = beg; j < end; ++j) {
        int s = csr_src[j];
        float w = dis[s] * dn;
        const float4 v = *(const float4*)(X + (size_t)s * 64 + c);
        ax += v.x * w;
        ay += v.y * w;
        az += v.z * w;
        aw += v.w * w;
    }
    float d2 = dn * dn;
    const float4 hv = *(const float4*)(X + (size_t)n * 64 + c);
    float4 r;
    r.x = ax + hv.x * d2;
    r.y = ay + hv.y * d2;
    r.z = az + hv.z * d2;
    r.w = aw + hv.w * d2;
    if (MODE == 1) {
        const float4 bv = *(const float4*)(b + c);
        r.x = 1.f / (1.f + expf(-(r.x + bv.x)));
        r.y = 1.f / (1.f + expf(-(r.y + bv.y)));
        r.z = 1.f / (1.f + expf(-(r.z + bv.z)));
        r.w = 1.f / (1.f + expf(-(r.w + bv.w)));
    }
    *(float4*)(out + (size_t)n * 64 + c) = r;
}

// ============================ launch ============================
extern "C" void kernel_launch(void* const* d_in, const int* in_sizes, int n_in,
                              void* d_out, int out_size, void* d_ws, size_t ws_size,
                              hipStream_t stream) {
    const float* x  = (const float*)d_in[0];
    const int*   ei = (const int*)d_in[1];
    const float* W1 = (const float*)d_in[2];
    const float* b1 = (const float*)d_in[3];
    const float* W2 = (const float*)d_in[4];
    const float* b2 = (const float*)d_in[5];

    constexpr int LAT = 64, HID = 96, OUTF = 64;
    const int E = in_sizes[1] / 2;
    const int N = in_sizes[0] / LAT;
    const int* src = ei;
    const int* dst = ei + E;

    const int B = 256;
    auto blocks = [](long total, int b) { return (int)((total + b - 1) / b); };

    const int ranges = (N + RNODES - 1) / RNODES;
    const int npad2 = ranges * RNODES;
    const int chunk = (E + G1 - 1) / G1;

    // ---- workspace layout (all fully rewritten every call; no memsets needed on fast path)
    size_t Npad = (size_t)((N + 1023) / 1024) * 1024;
    size_t Epad = (size_t)((E + 3) / 4) * 4;
    int* cnt      = (int*)d_ws;            // Npad
    int* cursor   = cnt + Npad;            // Npad
    int* cursmut  = cursor + Npad;         // Npad (fallback only)
    float* dis    = (float*)(cursmut + Npad);  // Npad
    int* partial  = (int*)(dis + Npad);    // 1024
    int* csr_src  = partial + 1024;        // Epad
    char* region  = (char*)(csr_src + Epad);
    // region phase A: hist (u16 G1*npad2) + colbase (int G1*npad2)
    unsigned short* hist = (unsigned short*)region;
    int* colbase = (int*)(region + ((size_t)G1 * npad2 * 2 + 15) / 16 * 16);
    // region phase B (after fill): Y (N*64) and H1 (N*96); Y reused as H2
    float* Y  = (float*)region;
    float* H1 = Y + (size_t)N * 64;

    size_t fixed = (4 * Npad + 1024 + Epad) * sizeof(int);
    size_t regionA = ((size_t)G1 * npad2 * 2 + 15) / 16 * 16 + (size_t)G1 * npad2 * sizeof(int);
    size_t regionB = ((size_t)N * 64 + (size_t)N * HID) * sizeof(float);
    size_t need_fast = fixed + (regionA > regionB ? regionA : regionB);
    size_t need_slow = fixed + regionB;

    bool fast = (ws_size >= need_fast) && (chunk < 65536) && (ranges <= 8) && (ws_size >= need_slow);

    if (fast) {
        // ---- atomic-free CSR build
        histo_kernel<<<G1, 256, 0, stream>>>(dst, hist, E, chunk, ranges, npad2);
        colsum_kernel<<<blocks(N, B), B, 0, stream>>>(hist, cnt, dis, N, npad2);
        int G = blocks(N, 1024);
        if (G <= 64) {
            scan_block_sum<<<G, 256, 0, stream>>>(cnt, partial, N);
            scan_partials<<<1, 64, 0, stream>>>(partial, G);
            scan_write<<<G, 256, 0, stream>>>(cnt, partial, cursor, N);
        } else {
            scan_kernel<<<1, 1024, 0, stream>>>(cnt, cursor, N);
        }
        colbase_kernel<<<blocks(N, B), B, 0, stream>>>(hist, cursor, colbase, N, npad2);
        fill_fast_kernel<<<G1, 256, 0, stream>>>(src, dst, colbase, csr_src, E, chunk, ranges, npad2);
    } else {
        // ---- fallback: device-atomic CSR build (round-4 proven semantics)
        zero_int_kernel<<<blocks(N, B), B, 0, stream>>>(cnt, N);
        degree_int_kernel<<<blocks(E, B), B, 0, stream>>>(dst, cnt, E);
        dis_from_cnt_kernel<<<blocks(N, B), B, 0, stream>>>(cnt, dis, N);
        int G = blocks(N, 1024);
        if (G <= 64) {
            scan_block_sum<<<G, 256, 0, stream>>>(cnt, partial, N);
            scan_partials<<<1, 64, 0, stream>>>(partial, G);
            scan_write<<<G, 256, 0, stream>>>(cnt, partial, cursor, N);
        } else {
            scan_kernel<<<1, 1024, 0, stream>>>(cnt, cursor, N);
        }
        hipMemcpyAsync(cursmut, cursor, (size_t)N * sizeof(int), hipMemcpyDeviceToDevice, stream);
        fill_atomic_kernel<<<blocks(E, B), B, 0, stream>>>(src, dst, cursmut, csr_src, E);
    }

    // ---- layer 1: Y = A_hat x ; H1 = relu(Y @ W1 + b1)   (GEMM commuted past agg)
    agg64_kernel<0><<<blocks((long)N * 16, B), B, 0, stream>>>(cursor, cnt, csr_src, dis, x,
                                                               nullptr, Y, N);
    gemm_tiled<LAT, HID, 6, true><<<blocks(N, 64), 256, 0, stream>>>(Y, W1, b1, H1, N);

    // ---- layer 2: H2 = H1 @ W2 ; out = sigmoid(A_hat H2 + b2)  (Y buffer reused as H2)
    gemm_tiled<HID, OUTF, 4, false><<<blocks(N, 64), 256, 0, stream>>>(H1, W2, nullptr, Y, N);
    agg64_kernel<1><<<blocks((long)N * 16, B), B, 0, stream>>>(cursor, cnt, csr_src, dis, Y, b2,
                                                               (float*)d_out, N);
}

// Round 6
// 222.794 us; speedup vs baseline: 8.8563x; 1.2437x over previous
//
#include <hip/hip_runtime.h>
#include <hip/hip_bf16.h>
#include <hip/hip_fp16.h>

// ==================== counting-sort CSR build (no device atomics) ====================
constexpr int G1 = 96;         // edge-chunk blocks
constexpr int RNODES = 12544;  // nodes per LDS range (u16 hist = 25088 B LDS)

// K1: per-(chunk, range) histogram via LDS packed-u16 atomics. grid = (G1, ranges)
__global__ __launch_bounds__(256) void histo_kernel(const int* __restrict__ dst,
                                                    unsigned short* __restrict__ hist,
                                                    int E, int chunk, int npad2) {
    __shared__ unsigned int h32[RNODES / 2];
    int g = blockIdx.x;
    int base = blockIdx.y * RNODES;
    int e0 = g * chunk;
    int e1 = min(e0 + chunk, E);
    for (int i = threadIdx.x; i < RNODES / 2; i += 256) h32[i] = 0;
    __syncthreads();
    for (int e = e0 + threadIdx.x; e < e1; e += 256) {
        int d = dst[e] - base;
        if (d >= 0 && d < RNODES) atomicAdd(&h32[d >> 1], 1u << ((d & 1) * 16));
    }
    __syncthreads();
    for (int i = threadIdx.x; i < RNODES; i += 256) {
        unsigned int v = (h32[i >> 1] >> ((i & 1) * 16)) & 0xFFFFu;
        hist[(size_t)g * npad2 + base + i] = (unsigned short)v;
    }
}

// K2: cnt[d] = sum_g hist[g][d]; also dis[d] = rsqrt(cnt+1)
__global__ void colsum_kernel(const unsigned short* __restrict__ hist, int* __restrict__ cnt,
                              float* __restrict__ dis, int N, int npad2) {
    int d = blockIdx.x * blockDim.x + threadIdx.x;
    if (d >= N) return;
    int s = 0;
    for (int g = 0; g < G1; ++g) s += hist[(size_t)g * npad2 + d];
    cnt[d] = s;
    dis[d] = rsqrtf((float)s + 1.0f);
}

// K3: colbase[g][d] = cursor[d] + sum_{g'<g} hist[g'][d]
__global__ void colbase_kernel(const unsigned short* __restrict__ hist,
                               const int* __restrict__ cursor, int* __restrict__ colbase,
                               int N, int npad2) {
    int d = blockIdx.x * blockDim.x + threadIdx.x;
    if (d >= N) return;
    int run = cursor[d];
    for (int g = 0; g < G1; ++g) {
        colbase[(size_t)g * npad2 + d] = run;
        run += hist[(size_t)g * npad2 + d];
    }
}

// K4: fill csr_src with LDS-only atomics. grid = (G1, ranges)
__global__ __launch_bounds__(256) void fill_fast_kernel(const int* __restrict__ src,
                                                        const int* __restrict__ dst,
                                                        const int* __restrict__ colbase,
                                                        int* __restrict__ csr_src,
                                                        int E, int chunk, int npad2) {
    __shared__ unsigned int c32[RNODES / 2];
    int g = blockIdx.x;
    int base = blockIdx.y * RNODES;
    int e0 = g * chunk;
    int e1 = min(e0 + chunk, E);
    for (int i = threadIdx.x; i < RNODES / 2; i += 256) c32[i] = 0;
    __syncthreads();
    for (int e = e0 + threadIdx.x; e < e1; e += 256) {
        int d = dst[e] - base;
        if (d >= 0 && d < RNODES) {
            unsigned int sh = (d & 1) * 16;
            unsigned int old = atomicAdd(&c32[d >> 1], 1u << sh);
            int local = (old >> sh) & 0xFFFF;
            int pos = colbase[(size_t)g * npad2 + base + d] + local;
            csr_src[pos] = src[e];
        }
    }
}

// ==================== multi-block scan (exclusive) ====================
__global__ __launch_bounds__(256) void scan_block_sum(const int* __restrict__ cnt,
                                                      int* __restrict__ partial, int N) {
    __shared__ int s[256];
    int t = threadIdx.x;
    int base = blockIdx.x * 1024 + t * 4;
    int v = 0;
#pragma unroll
    for (int k = 0; k < 4; ++k) {
        int idx = base + k;
        if (idx < N) v += cnt[idx];
    }
    s[t] = v;
    __syncthreads();
    for (int off = 128; off > 0; off >>= 1) {
        if (t < off) s[t] += s[t + off];
        __syncthreads();
    }
    if (t == 0) partial[blockIdx.x] = s[0];
}

__global__ __launch_bounds__(64) void scan_partials(int* __restrict__ partial, int G) {
    int t = threadIdx.x;
    int o = (t < G) ? partial[t] : 0;
    int v = o;
#pragma unroll
    for (int off = 1; off < 64; off <<= 1) {
        int u = __shfl_up(v, off, 64);
        if (t >= off) v += u;
    }
    if (t < G) partial[t] = v - o;
}

__global__ __launch_bounds__(256) void scan_write(const int* __restrict__ cnt,
                                                  const int* __restrict__ partial,
                                                  int* __restrict__ cursor, int N) {
    __shared__ int s[256];
    int t = threadIdx.x;
    int base = blockIdx.x * 1024 + t * 4;
    int loc[4];
    int v = 0;
#pragma unroll
    for (int k = 0; k < 4; ++k) {
        int idx = base + k;
        loc[k] = (idx < N) ? cnt[idx] : 0;
        v += loc[k];
    }
    s[t] = v;
    __syncthreads();
    for (int off = 1; off < 256; off <<= 1) {
        int add = (t >= off) ? s[t - off] : 0;
        __syncthreads();
        s[t] += add;
        __syncthreads();
    }
    int run = partial[blockIdx.x] + s[t] - v;
#pragma unroll
    for (int k = 0; k < 4; ++k) {
        int idx = base + k;
        if (idx < N) {
            cursor[idx] = run;
            run += loc[k];
        }
    }
}

__global__ __launch_bounds__(1024) void scan_kernel(const int* __restrict__ cnt,
                                                    int* __restrict__ cursor, int N) {
    constexpr int T = 1024;
    __shared__ int sums[T];
    int t = threadIdx.x;
    int ch = (N + T - 1) / T;
    int base = t * ch;
    int local = 0;
    for (int k = 0; k < ch; ++k) {
        int idx = base + k;
        if (idx < N) local += cnt[idx];
    }
    sums[t] = local;
    __syncthreads();
    for (int off = 1; off < T; off <<= 1) {
        int add = (t >= off) ? sums[t - off] : 0;
        __syncthreads();
        sums[t] += add;
        __syncthreads();
    }
    int run = sums[t] - local;
    for (int k = 0; k < ch; ++k) {
        int idx = base + k;
        if (idx < N) {
            cursor[idx] = run;
            run += cnt[idx];
        }
    }
}

// ==================== fallback CSR build (device atomics) ====================
__global__ void degree_int_kernel(const int* __restrict__ dst, int* __restrict__ cnt, int E) {
    int i = blockIdx.x * blockDim.x + threadIdx.x;
    if (i < E) atomicAdd(&cnt[dst[i]], 1);
}

__global__ void dis_from_cnt_kernel(const int* __restrict__ cnt, float* __restrict__ dis, int N) {
    int i = blockIdx.x * blockDim.x + threadIdx.x;
    if (i < N) dis[i] = rsqrtf((float)cnt[i] + 1.0f);
}

__global__ void zero_int_kernel(int* __restrict__ p, int N) {
    int i = blockIdx.x * blockDim.x + threadIdx.x;
    if (i < N) p[i] = 0;
}

__global__ void fill_atomic_kernel(const int* __restrict__ src, const int* __restrict__ dst,
                                   int* __restrict__ cursor_mut, int* __restrict__ csr_src,
                                   int E) {
    int e = blockIdx.x * blockDim.x + threadIdx.x;
    if (e >= E) return;
    int pos = atomicAdd(&cursor_mut[dst[e]], 1);
    csr_src[pos] = src[e];
}

// ==================== fp32 -> fp16 cast (8 elems/thread) ====================
__global__ void cast_f2h_kernel(const float* __restrict__ X, __half* __restrict__ Xh,
                                long total) {
    long i = ((long)blockIdx.x * blockDim.x + threadIdx.x) * 8;
    if (i >= total) return;
    float4 a = *(const float4*)(X + i);
    float4 b = *(const float4*)(X + i + 4);
    __half2 h[4];
    h[0] = __floats2half2_rn(a.x, a.y);
    h[1] = __floats2half2_rn(a.z, a.w);
    h[2] = __floats2half2_rn(b.x, b.y);
    h[3] = __floats2half2_rn(b.z, b.w);
    *(float4*)(Xh + i) = *(float4*)h;
}

// ==================== tiled GEMM, optional fused bias+relu, optional fp16 out ====================
template <int K, int F, int RF, bool BIAS_RELU, bool OUT_HALF>
__global__ __launch_bounds__(256) void gemm_tiled(const float* __restrict__ X,
                                                  const float* __restrict__ W,
                                                  const float* __restrict__ bias,
                                                  void* __restrict__ outv, int N) {
    constexpr int TM = 64, RN = 4;
    static_assert(F == 16 * RF, "");
    __shared__ float Xs[TM * (K + 1)];
    __shared__ float Ws[K * F];

    const int n0 = blockIdx.x * TM;
    const int t = threadIdx.x;

    for (int i = t; i < (K * F) / 4; i += 256)
        ((float4*)Ws)[i] = ((const float4*)W)[i];
    for (int i = t; i < (TM * K) / 4; i += 256) {
        int row = i / (K / 4);
        int c4 = (i - row * (K / 4)) * 4;
        float4 v = make_float4(0.f, 0.f, 0.f, 0.f);
        if (n0 + row < N) v = *(const float4*)(X + (size_t)(n0 + row) * K + c4);
        float* p = Xs + row * (K + 1) + c4;
        p[0] = v.x; p[1] = v.y; p[2] = v.z; p[3] = v.w;
    }
    __syncthreads();

    const int tn = t >> 4;
    const int tf = t & 15;
    float acc[RN][RF] = {};
#pragma unroll 4
    for (int k = 0; k < K; ++k) {
        float xv[RN];
#pragma unroll
        for (int i = 0; i < RN; ++i) xv[i] = Xs[(tn * RN + i) * (K + 1) + k];
        float wv[RF];
#pragma unroll
        for (int j = 0; j < RF / 2; ++j) {
            float2 w2 = *(const float2*)(Ws + k * F + tf * RF + 2 * j);
            wv[2 * j] = w2.x;
            wv[2 * j + 1] = w2.y;
        }
#pragma unroll
        for (int i = 0; i < RN; ++i)
#pragma unroll
            for (int j = 0; j < RF; ++j) acc[i][j] += xv[i] * wv[j];
    }

    float breg[RF];
    if (BIAS_RELU) {
#pragma unroll
        for (int j = 0; j < RF; ++j) breg[j] = bias[tf * RF + j];
    }
#pragma unroll
    for (int i = 0; i < RN; ++i) {
        int n = n0 + tn * RN + i;
        if (n < N) {
            float v[RF];
#pragma unroll
            for (int j = 0; j < RF; ++j) {
                v[j] = acc[i][j];
                if (BIAS_RELU) v[j] = fmaxf(v[j] + breg[j], 0.f);
            }
            if (OUT_HALF) {
                __half* op = (__half*)outv + (size_t)n * F + tf * RF;
#pragma unroll
                for (int j = 0; j < RF / 2; ++j)
                    *(__half2*)(op + 2 * j) = __floats2half2_rn(v[2 * j], v[2 * j + 1]);
            } else {
                float* op = (float*)outv + (size_t)n * F + tf * RF;
#pragma unroll
                for (int j = 0; j < RF; ++j) op[j] = v[j];
            }
        }
    }
}

// ==================== CSR gather-aggregate, fp16 table, 8 feats/thread ====================
// MODE 0: out = agg + X[n]*dn^2                 (pre-GEMM aggregation)
// MODE 1: out = sigmoid(agg + X[n]*dn^2 + b)    (final layer)
template <int MODE>
__global__ __launch_bounds__(256) void agg64h_kernel(const int* __restrict__ cursor,
                                                     const int* __restrict__ cnt,
                                                     const int* __restrict__ csr_src,
                                                     const float* __restrict__ dis,
                                                     const __half* __restrict__ Xh,
                                                     const float* __restrict__ b,
                                                     float* __restrict__ out, int N) {
    int i = blockIdx.x * 256 + threadIdx.x;
    int n = i >> 3;
    if (n >= N) return;
    int c = (i & 7) * 8;
    int beg = cursor[n];
    int end = beg + cnt[n];
    float dn = dis[n];
    float a[8] = {};
    for (int j = beg; j < end; ++j) {
        int s = csr_src[j];
        float w = dis[s] * dn;
        float4 raw = *(const float4*)(Xh + (size_t)s * 64 + c);
        const __half2* hp = (const __half2*)&raw;
#pragma unroll
        for (int q = 0; q < 4; ++q) {
            float2 f = __half22float2(hp[q]);
            a[2 * q]     += f.x * w;
            a[2 * q + 1] += f.y * w;
        }
    }
    float d2 = dn * dn;
    float4 sraw = *(const float4*)(Xh + (size_t)n * 64 + c);
    const __half2* sp = (const __half2*)&sraw;
    float r[8];
#pragma unroll
    for (int q = 0; q < 4; ++q) {
        float2 f = __half22float2(sp[q]);
        r[2 * q]     = a[2 * q] + f.x * d2;
        r[2 * q + 1] = a[2 * q + 1] + f.y * d2;
    }
    if (MODE == 1) {
#pragma unroll
        for (int q = 0; q < 8; ++q) {
            float bv = b[c + q];
            r[q] = 1.f / (1.f + expf(-(r[q] + bv)));
        }
    }
    *(float4*)(out + (size_t)n * 64 + c)     = make_float4(r[0], r[1], r[2], r[3]);
    *(float4*)(out + (size_t)n * 64 + c + 4) = make_float4(r[4], r[5], r[6], r[7]);
}

// ============================ launch ============================
extern "C" void kernel_launch(void* const* d_in, const int* in_sizes, int n_in,
                              void* d_out, int out_size, void* d_ws, size_t ws_size,
                              hipStream_t stream) {
    const float* x  = (const float*)d_in[0];
    const int*   ei = (const int*)d_in[1];
    const float* W1 = (const float*)d_in[2];
    const float* b1 = (const float*)d_in[3];
    const float* W2 = (const float*)d_in[4];
    const float* b2 = (const float*)d_in[5];

    constexpr int LAT = 64, HID = 96, OUTF = 64;
    const int E = in_sizes[1] / 2;
    const int N = in_sizes[0] / LAT;
    const int* src = ei;
    const int* dst = ei + E;

    const int B = 256;
    auto blocks = [](long total, int b) { return (int)((total + b - 1) / b); };

    const int ranges = (N + RNODES - 1) / RNODES;
    const int npad2 = ranges * RNODES;
    const int chunk = (E + G1 - 1) / G1;

    // ---- workspace layout (all fully rewritten every call; no memsets on fast path)
    size_t Npad = (size_t)((N + 1023) / 1024) * 1024;
    size_t Epad = (size_t)((E + 3) / 4) * 4;
    int* cnt      = (int*)d_ws;                // Npad
    int* cursor   = cnt + Npad;                // Npad
    int* cursmut  = cursor + Npad;             // Npad (fallback only)
    float* dis    = (float*)(cursmut + Npad);  // Npad
    int* partial  = (int*)(dis + Npad);        // 1024
    int* csr_src  = partial + 1024;            // Epad
    char* region  = (char*)(csr_src + Epad);
    // region phase A (CSR build): hist (u16 G1*npad2) + colbase (int G1*npad2)
    unsigned short* hist = (unsigned short*)region;
    int* colbase = (int*)(region + ((size_t)G1 * npad2 * 2 + 15) / 16 * 16);
    // region phase B (after build): Y fp32 (N*64) | H1 fp32 (N*96, first part doubles as xh/Y2h half)
    float*  Y   = (float*)region;
    float*  H1  = Y + (size_t)N * 64;
    __half* Th  = (__half*)H1;  // N*64 half gather table (xh, then Y2h); dead before H1 is written

    size_t fixed = (4 * Npad + 1024 + Epad) * sizeof(int);
    size_t regionA = ((size_t)G1 * npad2 * 2 + 15) / 16 * 16 + (size_t)G1 * npad2 * sizeof(int);
    size_t regionB = ((size_t)N * 64 + (size_t)N * HID) * sizeof(float);
    size_t need = fixed + (regionA > regionB ? regionA : regionB);

    bool fast = (ws_size >= need) && (chunk < 65536) && (ranges <= 8);

    if (fast) {
        // ---- atomic-free CSR build; histo/fill parallel over (chunk, range)
        dim3 g2(G1, ranges);
        histo_kernel<<<g2, 256, 0, stream>>>(dst, hist, E, chunk, npad2);
        colsum_kernel<<<blocks(N, B), B, 0, stream>>>(hist, cnt, dis, N, npad2);
        int G = blocks(N, 1024);
        if (G <= 64) {
            scan_block_sum<<<G, 256, 0, stream>>>(cnt, partial, N);
            scan_partials<<<1, 64, 0, stream>>>(partial, G);
            scan_write<<<G, 256, 0, stream>>>(cnt, partial, cursor, N);
        } else {
            scan_kernel<<<1, 1024, 0, stream>>>(cnt, cursor, N);
        }
        colbase_kernel<<<blocks(N, B), B, 0, stream>>>(hist, cursor, colbase, N, npad2);
        fill_fast_kernel<<<g2, 256, 0, stream>>>(src, dst, colbase, csr_src, E, chunk, npad2);
    } else {
        // ---- fallback: device-atomic CSR build
        zero_int_kernel<<<blocks(N, B), B, 0, stream>>>(cnt, N);
        degree_int_kernel<<<blocks(E, B), B, 0, stream>>>(dst, cnt, E);
        dis_from_cnt_kernel<<<blocks(N, B), B, 0, stream>>>(cnt, dis, N);
        int G = blocks(N, 1024);
        if (G <= 64) {
            scan_block_sum<<<G, 256, 0, stream>>>(cnt, partial, N);
            scan_partials<<<1, 64, 0, stream>>>(partial, G);
            scan_write<<<G, 256, 0, stream>>>(cnt, partial, cursor, N);
        } else {
            scan_kernel<<<1, 1024, 0, stream>>>(cnt, cursor, N);
        }
        hipMemcpyAsync(cursmut, cursor, (size_t)N * sizeof(int), hipMemcpyDeviceToDevice, stream);
        fill_atomic_kernel<<<blocks(E, B), B, 0, stream>>>(src, dst, cursmut, csr_src, E);
    }

    // ---- layer 1: xh = half(x); Y = A_hat x (fp16 gather, fp32 accum); H1 = relu(Y@W1 + b1)
    cast_f2h_kernel<<<blocks((long)N * 8, B), B, 0, stream>>>(x, Th, (long)N * 64);
    agg64h_kernel<0><<<blocks((long)N * 8, B), B, 0, stream>>>(cursor, cnt, csr_src, dis, Th,
                                                               nullptr, Y, N);
    gemm_tiled<LAT, HID, 6, true, false><<<blocks(N, 64), 256, 0, stream>>>(Y, W1, b1, H1, N);

    // ---- layer 2: Y2h = half(H1 @ W2); out = sigmoid(A_hat Y2 + b2)
    //      (Y2h aliases Y's space — Y is dead after gemm1)
    gemm_tiled<HID, OUTF, 4, false, true><<<blocks(N, 64), 256, 0, stream>>>(H1, W2, nullptr,
                                                                             (void*)Y, N);
    agg64h_kernel<1><<<blocks((long)N * 8, B), B, 0, stream>>>(cursor, cnt, csr_src, dis,
                                                               (const __half*)Y, b2,
                                                               (float*)d_out, N);
}